// Round 1
// baseline (937.525 us; speedup 1.0000x reference)
//
#include <hip/hip_runtime.h>

// InterHT score: per row b
//   hm,ha = head[b, :512], head[b, 512:]; tm,ta = tail[b,:512], tail[b,512:]
//   all four L2-normalized (v / max(||v||, 1e-12))
//   d = hm_n*(ta_n + 1) + rel[rid[b]] - tm_n*(ha_n + 1)
//   out[b] = -sqrt(sum(d*d))
//
// One wave (64 lanes) per row-CHUNK; lane l holds elements {4l..4l+3, 256+4l..4l+3+256}
// of each 512-wide part (2x 16B vector loads, fully coalesced 1KB segments).
//
// v2: 8-row chunk per wave with 1-deep software pipeline.
//   Per iteration issue order:  rel gather (cur) -> rid+8 nt loads (next) -> compute (cur).
//   vmcnt is FIFO, so the wait before compute drains only up to the current row's
//   rel loads and leaves the next row's 9 loads in flight across the shfl-reduce
//   tail. Eliminates the convoy stall of the 1-row/wave version (~4.2 TB/s).
//
// Note: __builtin_nontemporal_load requires a NATIVE clang vector type;
// HIP's float4 is a class. Use ext_vector_type(4) for streamed loads.
// nt only on head/tail (streamed); rel table (2 MB) must stay L2-cached.

constexpr int EMB = 512;
constexpr int CHUNK = 8;          // rows per wave

typedef float fvec4 __attribute__((ext_vector_type(4)));

__device__ __forceinline__ float dot4(const fvec4 v) {
    return v.x * v.x + v.y * v.y + v.z * v.z + v.w * v.w;
}

__device__ __forceinline__ float wave_allreduce(float v) {
#pragma unroll
    for (int off = 32; off >= 1; off >>= 1)
        v += __shfl_xor(v, off, 64);
    return v;
}

struct Row {
    fvec4 hm0, hm1, ha0, ha1, tm0, tm1, ta0, ta1;
};

__device__ __forceinline__ void load_row(const float* __restrict__ head,
                                         const float* __restrict__ tail,
                                         int row, int lane, Row& R) {
    const fvec4* h = reinterpret_cast<const fvec4*>(head) + (size_t)row * (2 * EMB / 4);
    const fvec4* t = reinterpret_cast<const fvec4*>(tail) + (size_t)row * (2 * EMB / 4);
    R.hm0 = __builtin_nontemporal_load(&h[lane]);
    R.hm1 = __builtin_nontemporal_load(&h[64 + lane]);
    R.ha0 = __builtin_nontemporal_load(&h[128 + lane]);
    R.ha1 = __builtin_nontemporal_load(&h[192 + lane]);
    R.tm0 = __builtin_nontemporal_load(&t[lane]);
    R.tm1 = __builtin_nontemporal_load(&t[64 + lane]);
    R.ta0 = __builtin_nontemporal_load(&t[128 + lane]);
    R.ta1 = __builtin_nontemporal_load(&t[192 + lane]);
}

__device__ __forceinline__ void process_row(const Row& R, const fvec4 r0, const fvec4 r1,
                                            int lane, int row, float* __restrict__ out) {
    // four L2 norms (wave all-reduce each; 4 independent chains, compiler interleaves)
    const float s_hm = wave_allreduce(dot4(R.hm0) + dot4(R.hm1));
    const float s_ha = wave_allreduce(dot4(R.ha0) + dot4(R.ha1));
    const float s_tm = wave_allreduce(dot4(R.tm0) + dot4(R.tm1));
    const float s_ta = wave_allreduce(dot4(R.ta0) + dot4(R.ta1));

    const float i_hm = 1.0f / fmaxf(sqrtf(s_hm), 1e-12f);
    const float i_ha = 1.0f / fmaxf(sqrtf(s_ha), 1e-12f);
    const float i_tm = 1.0f / fmaxf(sqrtf(s_tm), 1e-12f);
    const float i_ta = 1.0f / fmaxf(sqrtf(s_ta), 1e-12f);

    float acc = 0.0f;
    auto accum = [&](float hm, float ha, float tm, float ta, float rr) {
        const float d = hm * i_hm * (ta * i_ta + 1.0f) + rr
                      - tm * i_tm * (ha * i_ha + 1.0f);
        acc = fmaf(d, d, acc);
    };
    accum(R.hm0.x, R.ha0.x, R.tm0.x, R.ta0.x, r0.x);
    accum(R.hm0.y, R.ha0.y, R.tm0.y, R.ta0.y, r0.y);
    accum(R.hm0.z, R.ha0.z, R.tm0.z, R.ta0.z, r0.z);
    accum(R.hm0.w, R.ha0.w, R.tm0.w, R.ta0.w, r0.w);
    accum(R.hm1.x, R.ha1.x, R.tm1.x, R.ta1.x, r1.x);
    accum(R.hm1.y, R.ha1.y, R.tm1.y, R.ta1.y, r1.y);
    accum(R.hm1.z, R.ha1.z, R.tm1.z, R.ta1.z, r1.z);
    accum(R.hm1.w, R.ha1.w, R.tm1.w, R.ta1.w, r1.w);

    acc = wave_allreduce(acc);
    if (lane == 0) __builtin_nontemporal_store(-sqrtf(acc), &out[row]);
}

__global__ __launch_bounds__(256, 4) void interht_score_kernel(
    const float* __restrict__ head,
    const float* __restrict__ tail,
    const float* __restrict__ rel_emb,
    const int* __restrict__ rel_id,
    float* __restrict__ out,
    int batch)
{
    const int lane = threadIdx.x & 63;
    const int wave = threadIdx.x >> 6;
    const int gw   = (blockIdx.x << 2) + wave;       // global wave id

    int row = gw * CHUNK;
    const int row_end = min(row + CHUNK, batch);
    if (row >= row_end) return;

    // pipeline prologue: current row's rid + head/tail in flight
    Row cur, nxt;
    int rid_cur = rel_id[row];
    load_row(head, tail, row, lane, cur);

#pragma unroll 2
    for (; row < row_end; ) {
        // (1) rel gather for CURRENT row (depends only on rid_cur, issued first
        //     so the compute-wait below does not drain the next row's loads)
        const fvec4* r = reinterpret_cast<const fvec4*>(rel_emb)
                       + (size_t)rid_cur * (EMB / 4);
        const fvec4 r0 = r[lane];
        const fvec4 r1 = r[64 + lane];

        // (2) prefetch NEXT row: rid then 8 nt loads (stay in flight across compute)
        const int nrow = row + 1;
        int rid_nxt = 0;
        if (nrow < row_end) {
            rid_nxt = rel_id[nrow];
            load_row(head, tail, nrow, lane, nxt);
        }

        // (3) compute CURRENT row (waits only up to r0/r1 in the vmcnt FIFO)
        process_row(cur, r0, r1, lane, row, out);

        cur = nxt;
        rid_cur = rid_nxt;
        row = nrow;
    }
}

extern "C" void kernel_launch(void* const* d_in, const int* in_sizes, int n_in,
                              void* d_out, int out_size, void* d_ws, size_t ws_size,
                              hipStream_t stream) {
    const float* head    = (const float*)d_in[0];
    const float* tail    = (const float*)d_in[1];
    const float* rel_emb = (const float*)d_in[2];
    const int*   rel_id  = (const int*)d_in[3];
    float* out = (float*)d_out;

    const int batch = in_sizes[3];               // relation_id count = BATCH
    const int rows_per_block = 4 * CHUNK;        // 4 waves x CHUNK rows
    const int grid = (batch + rows_per_block - 1) / rows_per_block;

    interht_score_kernel<<<grid, 256, 0, stream>>>(head, tail, rel_emb, rel_id,
                                                   out, batch);
}